// Round 12
// baseline (857.933 us; speedup 1.0000x reference)
//
#include <hip/hip_runtime.h>
#include <hip/hip_bf16.h>
#include <stdint.h>
#include <type_traits>

#define NROWS   65536
#define EPS     1e-5f
#define BM      16
#define NBLK    (NROWS / BM)   // 4096

typedef __attribute__((ext_vector_type(8))) short short8;
typedef __attribute__((ext_vector_type(4))) float f32x4;

__device__ __forceinline__ unsigned short f2bf(float f) {
    unsigned u = __float_as_uint(f);
    unsigned r = (u + 0x7FFFu + ((u >> 16) & 1u)) >> 16;
    return (unsigned short)r;
}

// LDS cell addressing: k-packed cells of 8 bf16 (16 B), cell(kg, r) for 16 rows,
// XOR-swizzled so the 4 lg-chunks of an A-fragment read start at different banks.
__device__ __forceinline__ int cellb(int kg, int r) {
    return (((kg << 4) + r) << 4) ^ ((kg & 3) << 5);
}

// ---------------- K0: weights -> bf16, MFMA-fragment-packed (16x16) ----------------
// Fragment order: [tile=n>>4][kt][lane][j], elem: n = tile*16+(l&15),
// k = kt*32+(l>>4)*8+j.  A wave's B-load per K-step = contiguous 1 KB. (proven R4-R11)
__global__ void k_prep(const float* __restrict__ W1, const float* __restrict__ W2,
                       const float* __restrict__ W3,
                       unsigned short* __restrict__ w1p, unsigned short* __restrict__ w2p,
                       unsigned short* __restrict__ w3p) {
    int idx = blockIdx.x * 256 + threadIdx.x;
    if (idx < 131072) {                      // W1: K=256 (kt 0..7), N=512 (tile 0..31)
        int j = idx & 7, l = (idx >> 3) & 63, kt = (idx >> 9) & 7, tile = idx >> 12;
        int n = tile * 16 + (l & 15);
        int k = kt * 32 + (l >> 4) * 8 + j;
        w1p[idx] = f2bf(W1[k * 512 + n]);
    } else if (idx < 393216) {               // W2: K=512 (kt 0..15), N=512 (tile 0..31)
        int i2 = idx - 131072;
        int j = i2 & 7, l = (i2 >> 3) & 63, kt = (i2 >> 9) & 15, tile = i2 >> 13;
        int n = tile * 16 + (l & 15);
        int k = kt * 32 + (l >> 4) * 8 + j;
        w2p[i2] = f2bf(W2[k * 512 + n]);
    } else if (idx < 524288) {               // W3: K=512 (kt 0..15), N=256 (tile 0..15)
        int i3 = idx - 393216;
        int j = i3 & 7, l = (i3 >> 3) & 63, kt = (i3 >> 9) & 15, tile = i3 >> 13;
        int n = tile * 16 + (l & 15);
        int k = kt * 32 + (l >> 4) * 8 + j;
        w3p[i3] = f2bf(W3[k * 256 + n]);
    }
}

// ---------------- K1: fused MLP chain ----------------
// 4096 blocks x 256 thr (4 waves), block owns 16 batch rows. Goal: 2 independent
// blocks/CU (empirical waves/CU = 1024/VGPR: R2 64->15 waves, R4/R9/R11
// 100-128->7.4 waves = 1 block) so one block's barriers are filled by the other.
// Layers 1-2: wave w owns cols [w*128,(w+1)*128) = 8 tiles, in TWO compile-time
// col-passes of 4 tiles (integral_constant P; sched_barrier(0) between passes
// prevents R8-style interleave; P compile-time keeps agg[] statically indexed,
// rule #20). Layer3: wave owns 4 tiles (64 cols).
// LDS: h1s 16 KB [0,16K), ebuf 8 KB [16K,24K). zbuf (fp32 16KB) aliases h1s.
// Regs: agg 32 + c 16 + A 8 + B 32 + misc ~25 = ~115 <= 128 cap (256,4).
// B-frags DIRECT from L2 (R5: LDS-staging = 2.3x worse). Ping-pong pipeline (R11).
__global__ __launch_bounds__(256, 4)
void k_fused(const float* __restrict__ x,
             const unsigned short* __restrict__ w1p,
             const unsigned short* __restrict__ w2p,
             const unsigned short* __restrict__ w3p,
             const float* __restrict__ b1, const float* __restrict__ b2,
             const float* __restrict__ b3,
             float* __restrict__ out) {
    __shared__ __align__(16) unsigned char smem[24576];
    unsigned char* h1b = smem;            // 16 KB
    unsigned char* ebb = smem + 16384;    // 8 KB
    float* zbuf = (float*)smem;

    const int tid = threadIdx.x;
    const int w   = tid >> 6;       // 0..3
    const int l   = tid & 63;
    const int l15 = l & 15;
    const int lg  = l >> 4;
    const int blk = blockIdx.x;
    const int row0 = blk * BM;

    // staging mapping: kg = tid&15 (coalesced 512B per 16 lanes), row = tid>>4
    const int skg = tid & 15;
    const int sr  = tid >> 4;       // 0..15
    const float* xrow = x + (size_t)(row0 + sr) * 768;

    f32x4 agg[8];
#pragma unroll
    for (int q = 0; q < 8; ++q) agg[q] = (f32x4){0.f, 0.f, 0.f, 0.f};

    for (int e = 0; e < 3; ++e) {
        const int na = e >> 1;              // 0,0,1
        const int nb = ((e + 1) >> 1) + 1;  // 1,2,2

        // ---- stage e = x[na] + x[nb] into ebuf (bf16, k-packed) ----
#pragma unroll
        for (int h = 0; h < 2; ++h) {
            int kg = skg + h * 16;
            const float* pa = xrow + na * 256 + kg * 8;
            const float* pb = xrow + nb * 256 + kg * 8;
            float4 a0 = *(const float4*)(pa);
            float4 a1 = *(const float4*)(pa + 4);
            float4 bv0 = *(const float4*)(pb);
            float4 bv1 = *(const float4*)(pb + 4);
            uint4 pk;
            pk.x = (unsigned)f2bf(a0.x + bv0.x) | ((unsigned)f2bf(a0.y + bv0.y) << 16);
            pk.y = (unsigned)f2bf(a0.z + bv0.z) | ((unsigned)f2bf(a0.w + bv0.w) << 16);
            pk.z = (unsigned)f2bf(a1.x + bv1.x) | ((unsigned)f2bf(a1.y + bv1.y) << 16);
            pk.w = (unsigned)f2bf(a1.z + bv1.z) | ((unsigned)f2bf(a1.w + bv1.w) << 16);
            *(uint4*)(ebb + cellb(kg, sr)) = pk;
        }

        // ---- layer1: c1 = e @ W1 (K=256, 8 kt, 2 col-passes, ping-pong) ----
        auto layer1_pass = [&](auto Pc, bool first) {
            constexpr int P = Pc.value;
            f32x4 c1[4];
#pragma unroll
            for (int nt = 0; nt < 4; ++nt) c1[nt] = (f32x4){0.f, 0.f, 0.f, 0.f};
            short8 aP, aQ, bP[4], bQ[4];
#pragma unroll
            for (int nt = 0; nt < 4; ++nt)
                bP[nt] = *(const short8*)(w1p + (((w * 8 + P * 4 + nt) * 8) * 64 + l) * 8);
            if (first) __syncthreads();   // ebuf ready; prev-edge h1 reads all done
            aP = *(const short8*)(ebb + cellb(lg, l15));
#pragma unroll 1
            for (int kt = 0; kt < 8; kt += 2) {
                aQ = *(const short8*)(ebb + cellb((kt + 1) * 4 + lg, l15));
#pragma unroll
                for (int nt = 0; nt < 4; ++nt)
                    bQ[nt] = *(const short8*)(w1p + (((w * 8 + P * 4 + nt) * 8 + kt + 1) * 64 + l) * 8);
                __builtin_amdgcn_s_setprio(1);
#pragma unroll
                for (int nt = 0; nt < 4; ++nt)
                    c1[nt] = __builtin_amdgcn_mfma_f32_16x16x32_bf16(aP, bP[nt], c1[nt], 0, 0, 0);
                __builtin_amdgcn_s_setprio(0);
                if (kt + 2 < 8) {
                    aP = *(const short8*)(ebb + cellb((kt + 2) * 4 + lg, l15));
#pragma unroll
                    for (int nt = 0; nt < 4; ++nt)
                        bP[nt] = *(const short8*)(w1p + (((w * 8 + P * 4 + nt) * 8 + kt + 2) * 64 + l) * 8);
                }
                __builtin_amdgcn_s_setprio(1);
#pragma unroll
                for (int nt = 0; nt < 4; ++nt)
                    c1[nt] = __builtin_amdgcn_mfma_f32_16x16x32_bf16(aQ, bQ[nt], c1[nt], 0, 0, 0);
                __builtin_amdgcn_s_setprio(0);
            }
            // epilogue: relu(c1+b1) -> h1s (bf16, k-packed)
#pragma unroll
            for (int nt = 0; nt < 4; ++nt) {
                int c = (w * 8 + P * 4 + nt) * 16 + l15;
                float bias = b1[c];
#pragma unroll
                for (int reg = 0; reg < 4; ++reg) {
                    int r = lg * 4 + reg;
                    float v = c1[nt][reg] + bias;
                    v = v > 0.f ? v : 0.f;
                    *(unsigned short*)(h1b + cellb(c >> 3, r) + ((c & 7) << 1)) = f2bf(v);
                }
            }
        };
        layer1_pass(std::integral_constant<int, 0>{}, true);
        __builtin_amdgcn_sched_barrier(0);
        layer1_pass(std::integral_constant<int, 1>{}, false);

        // ---- layer2: c2 = h1 @ W2 (K=512, 16 kt, 2 col-passes, ping-pong) ----
        auto layer2_pass = [&](auto Pc, bool first) {
            constexpr int P = Pc.value;
            f32x4 c2[4];
#pragma unroll
            for (int nt = 0; nt < 4; ++nt) c2[nt] = (f32x4){0.f, 0.f, 0.f, 0.f};
            short8 aP, aQ, bP[4], bQ[4];
#pragma unroll
            for (int nt = 0; nt < 4; ++nt)
                bP[nt] = *(const short8*)(w2p + (((w * 8 + P * 4 + nt) * 16) * 64 + l) * 8);
            if (first) __syncthreads();   // h1s ready; ebuf reads done
            aP = *(const short8*)(h1b + cellb(lg, l15));
#pragma unroll 1
            for (int kt = 0; kt < 16; kt += 2) {
                aQ = *(const short8*)(h1b + cellb((kt + 1) * 4 + lg, l15));
#pragma unroll
                for (int nt = 0; nt < 4; ++nt)
                    bQ[nt] = *(const short8*)(w2p + (((w * 8 + P * 4 + nt) * 16 + kt + 1) * 64 + l) * 8);
                __builtin_amdgcn_s_setprio(1);
#pragma unroll
                for (int nt = 0; nt < 4; ++nt)
                    c2[nt] = __builtin_amdgcn_mfma_f32_16x16x32_bf16(aP, bP[nt], c2[nt], 0, 0, 0);
                __builtin_amdgcn_s_setprio(0);
                if (kt + 2 < 16) {
                    aP = *(const short8*)(h1b + cellb((kt + 2) * 4 + lg, l15));
#pragma unroll
                    for (int nt = 0; nt < 4; ++nt)
                        bP[nt] = *(const short8*)(w2p + (((w * 8 + P * 4 + nt) * 16 + kt + 2) * 64 + l) * 8);
                }
                __builtin_amdgcn_s_setprio(1);
#pragma unroll
                for (int nt = 0; nt < 4; ++nt)
                    c2[nt] = __builtin_amdgcn_mfma_f32_16x16x32_bf16(aQ, bQ[nt], c2[nt], 0, 0, 0);
                __builtin_amdgcn_s_setprio(0);
            }
            // relu(c2+b2) accumulated into agg (static indices: P compile-time)
#pragma unroll
            for (int nt = 0; nt < 4; ++nt) {
                float bias = b2[(w * 8 + P * 4 + nt) * 16 + l15];
#pragma unroll
                for (int reg = 0; reg < 4; ++reg) {
                    float v = c2[nt][reg] + bias;
                    agg[P * 4 + nt][reg] += (v > 0.f ? v : 0.f);
                }
            }
        };
        layer2_pass(std::integral_constant<int, 0>{}, true);
        __builtin_amdgcn_sched_barrier(0);
        layer2_pass(std::integral_constant<int, 1>{}, false);
        // next edge's post-stage barrier (in layer1_pass first=true) orders h1s/ebuf reuse
    }

    // ---- agg -> h1s (bf16, k-packed) ----
    __syncthreads();   // all waves done reading h1s in layer2
#pragma unroll
    for (int q = 0; q < 8; ++q) {
        int c = (w * 8 + q) * 16 + l15;
#pragma unroll
        for (int reg = 0; reg < 4; ++reg) {
            int r = lg * 4 + reg;
            *(unsigned short*)(h1b + cellb(c >> 3, r) + ((c & 7) << 1)) = f2bf(agg[q][reg]);
        }
    }

    // ---- layer3: z = agg @ W3 + b3 (K=512, wave owns 64 cols, ping-pong) ----
    f32x4 c3[4];
#pragma unroll
    for (int nt = 0; nt < 4; ++nt) c3[nt] = (f32x4){0.f, 0.f, 0.f, 0.f};
    {
        short8 aP, aQ, bP[4], bQ[4];
#pragma unroll
        for (int nt = 0; nt < 4; ++nt)
            bP[nt] = *(const short8*)(w3p + (((w * 4 + nt) * 16) * 64 + l) * 8);
        __syncthreads();   // h1s(agg) ready
        aP = *(const short8*)(h1b + cellb(lg, l15));
#pragma unroll 1
        for (int kt = 0; kt < 16; kt += 2) {
            aQ = *(const short8*)(h1b + cellb((kt + 1) * 4 + lg, l15));
#pragma unroll
            for (int nt = 0; nt < 4; ++nt)
                bQ[nt] = *(const short8*)(w3p + (((w * 4 + nt) * 16 + kt + 1) * 64 + l) * 8);
            __builtin_amdgcn_s_setprio(1);
#pragma unroll
            for (int nt = 0; nt < 4; ++nt)
                c3[nt] = __builtin_amdgcn_mfma_f32_16x16x32_bf16(aP, bP[nt], c3[nt], 0, 0, 0);
            __builtin_amdgcn_s_setprio(0);
            if (kt + 2 < 16) {
                aP = *(const short8*)(h1b + cellb((kt + 2) * 4 + lg, l15));
#pragma unroll
                for (int nt = 0; nt < 4; ++nt)
                    bP[nt] = *(const short8*)(w3p + (((w * 4 + nt) * 16 + kt + 2) * 64 + l) * 8);
            }
            __builtin_amdgcn_s_setprio(1);
#pragma unroll
            for (int nt = 0; nt < 4; ++nt)
                c3[nt] = __builtin_amdgcn_mfma_f32_16x16x32_bf16(aQ, bQ[nt], c3[nt], 0, 0, 0);
            __builtin_amdgcn_s_setprio(0);
        }
    }

    // ---- z epilogue: zbuf (aliases h1s) for coalesced float4 stores ----
    __syncthreads();   // layer3 ds_reads done before overwriting as zbuf
#pragma unroll
    for (int nt = 0; nt < 4; ++nt) {
        int c = (w * 4 + nt) * 16 + l15;
        float bias = b3[c];
#pragma unroll
        for (int reg = 0; reg < 4; ++reg) {
            int r = lg * 4 + reg;
            zbuf[r * 256 + c] = c3[nt][reg] + bias;
        }
    }
    __syncthreads();
    {
        const float4* zb4 = (const float4*)zbuf;
        float4* o4 = (float4*)(out + (size_t)row0 * 256);
#pragma unroll
        for (int i = 0; i < 4; ++i)
            o4[tid + i * 256] = zb4[tid + i * 256];
    }
}

// ---------------- K2a: per-chunk column sums of z ----------------
// 1024 blocks x 256 thr; block b sums rows [b*64, b*64+64) for its column.
__global__ void k_stats1(const float* __restrict__ out,
                         float* __restrict__ psum, float* __restrict__ psumsq) {
    int b = blockIdx.x, c = threadIdx.x;
    const float* p = out + (size_t)b * 64 * 256 + c;
    float s = 0.f, q = 0.f;
#pragma unroll 8
    for (int r = 0; r < 64; ++r) {
        float v = p[r * 256];
        s += v;
        q += v * v;
    }
    psum[c * 1024 + b] = s;
    psumsq[c * 1024 + b] = q;
}

// ---------------- K2b: reduce 1024 partials -> scale/shift ----------------
__global__ void k_stats2(const float* __restrict__ psum, const float* __restrict__ psumsq,
                         const float* __restrict__ gamma, const float* __restrict__ beta,
                         float* __restrict__ scale, float* __restrict__ shift) {
    int f = blockIdx.x, t = threadIdx.x;
    const float* ps = psum + f * 1024;
    const float* pq = psumsq + f * 1024;
    float s = 0.f, q = 0.f;
#pragma unroll
    for (int i = 0; i < 4; ++i) {
        s += ps[t + i * 256];
        q += pq[t + i * 256];
    }
#pragma unroll
    for (int o = 32; o > 0; o >>= 1) {
        s += __shfl_down(s, o);
        q += __shfl_down(q, o);
    }
    __shared__ float ls[4], lq[4];
    if ((t & 63) == 0) { ls[t >> 6] = s; lq[t >> 6] = q; }
    __syncthreads();
    if (t == 0) {
        s = ls[0] + ls[1] + ls[2] + ls[3];
        q = lq[0] + lq[1] + lq[2] + lq[3];
        float mu  = s * (1.f / 65536.f);
        float var = q * (1.f / 65536.f) - mu * mu;
        float sc  = gamma[f] * rsqrtf(var + EPS);
        scale[f] = sc;
        shift[f] = beta[f] - mu * sc;
    }
}

// ---------------- K3: in-place normalize of d_out ----------------
__global__ void k_norm(float4* __restrict__ out4, const float4* __restrict__ scale4,
                       const float4* __restrict__ shift4, int n4) {
    int i = blockIdx.x * blockDim.x + threadIdx.x;
    int stride = gridDim.x * blockDim.x;
    for (; i < n4; i += stride) {
        float4 v = out4[i];
        float4 sc = scale4[i & 63];
        float4 sh = shift4[i & 63];
        v.x = v.x * sc.x + sh.x;
        v.y = v.y * sc.y + sh.y;
        v.z = v.z * sc.z + sh.z;
        v.w = v.w * sc.w + sh.w;
        out4[i] = v;
    }
}

extern "C" void kernel_launch(void* const* d_in, const int* in_sizes, int n_in,
                              void* d_out, int out_size, void* d_ws, size_t ws_size,
                              hipStream_t stream) {
    const float* x     = (const float*)d_in[0];
    const float* W1    = (const float*)d_in[1];
    const float* b1    = (const float*)d_in[2];
    const float* W2    = (const float*)d_in[3];
    const float* b2    = (const float*)d_in[4];
    const float* W3    = (const float*)d_in[5];
    const float* b3    = (const float*)d_in[6];
    const float* gamma = (const float*)d_in[7];
    const float* beta  = (const float*)d_in[8];

    char* ws = (char*)d_ws;
    unsigned short* w1p = (unsigned short*)(ws);            // 256 KB
    unsigned short* w2p = (unsigned short*)(ws + 262144);   // 512 KB
    unsigned short* w3p = (unsigned short*)(ws + 786432);   // 256 KB
    float* psum   = (float*)(ws + 1048576);                 // 1 MB
    float* psumsq = (float*)(ws + 2097152);                 // 1 MB
    float* scale  = (float*)(ws + 3145728);                 // 1 KB
    float* shift  = (float*)(ws + 3146752);                 // 1 KB

    float* out = (float*)d_out;

    k_prep<<<2048, 256, 0, stream>>>(W1, W2, W3, w1p, w2p, w3p);
    k_fused<<<NBLK, 256, 0, stream>>>(x, w1p, w2p, w3p, b1, b2, b3, out);
    k_stats1<<<1024, 256, 0, stream>>>(out, psum, psumsq);
    k_stats2<<<256, 256, 0, stream>>>(psum, psumsq, gamma, beta, scale, shift);
    k_norm<<<2048, 256, 0, stream>>>((float4*)out, (const float4*)scale, (const float4*)shift,
                                     (NROWS * 256) / 4);
}

// Round 13
// 236.151 us; speedup vs baseline: 3.6330x; 3.6330x over previous
//
#include <hip/hip_runtime.h>
#include <hip/hip_bf16.h>
#include <stdint.h>

#define NROWS   65536
#define EPS     1e-5f
#define BM      32
#define NBLK    (NROWS / BM)   // 2048

typedef __attribute__((ext_vector_type(8))) short short8;
typedef __attribute__((ext_vector_type(4))) float f32x4;

__device__ __forceinline__ unsigned short f2bf(float f) {
    unsigned u = __float_as_uint(f);
    unsigned r = (u + 0x7FFFu + ((u >> 16) & 1u)) >> 16;
    return (unsigned short)r;
}

// LDS cell addressing: k-packed cells of 8 bf16 (16 B), cell(kg, r) for 32 rows,
// XOR-swizzled (proven R4-R11; writer+reader agree).
__device__ __forceinline__ int cellb(int kg, int r) {
    return (((kg << 5) + r) << 4) ^ ((kg & 3) << 5);
}

__device__ __forceinline__ uint4 pack8(float4 a0, float4 a1, float4 b0, float4 b1) {
    uint4 pk;
    pk.x = (unsigned)f2bf(a0.x + b0.x) | ((unsigned)f2bf(a0.y + b0.y) << 16);
    pk.y = (unsigned)f2bf(a0.z + b0.z) | ((unsigned)f2bf(a0.w + b0.w) << 16);
    pk.z = (unsigned)f2bf(a1.x + b1.x) | ((unsigned)f2bf(a1.y + b1.y) << 16);
    pk.w = (unsigned)f2bf(a1.z + b1.z) | ((unsigned)f2bf(a1.w + b1.w) << 16);
    return pk;
}

// ---------------- K0: weights -> bf16, MFMA-fragment-packed (16x16) ----------------
// Fragment order: [tile=n>>4][kt][lane][j], elem: n = tile*16+(l&15),
// k = kt*32+(l>>4)*8+j.  A wave's B-load per K-step = contiguous 1 KB. (proven R4-R11)
__global__ void k_prep(const float* __restrict__ W1, const float* __restrict__ W2,
                       const float* __restrict__ W3,
                       unsigned short* __restrict__ w1p, unsigned short* __restrict__ w2p,
                       unsigned short* __restrict__ w3p) {
    int idx = blockIdx.x * 256 + threadIdx.x;
    if (idx < 131072) {                      // W1: K=256 (kt 0..7), N=512 (tile 0..31)
        int j = idx & 7, l = (idx >> 3) & 63, kt = (idx >> 9) & 7, tile = idx >> 12;
        int n = tile * 16 + (l & 15);
        int k = kt * 32 + (l >> 4) * 8 + j;
        w1p[idx] = f2bf(W1[k * 512 + n]);
    } else if (idx < 393216) {               // W2: K=512 (kt 0..15), N=512 (tile 0..31)
        int i2 = idx - 131072;
        int j = i2 & 7, l = (i2 >> 3) & 63, kt = (i2 >> 9) & 15, tile = i2 >> 13;
        int n = tile * 16 + (l & 15);
        int k = kt * 32 + (l >> 4) * 8 + j;
        w2p[i2] = f2bf(W2[k * 512 + n]);
    } else if (idx < 524288) {               // W3: K=512 (kt 0..15), N=256 (tile 0..15)
        int i3 = idx - 393216;
        int j = i3 & 7, l = (i3 >> 3) & 63, kt = (i3 >> 9) & 15, tile = i3 >> 13;
        int n = tile * 16 + (l & 15);
        int k = kt * 32 + (l >> 4) * 8 + j;
        w3p[i3] = f2bf(W3[k * 256 + n]);
    }
}

// ---------------- K1: fused MLP chain — EDGE-INNER (R13) ----------------
// 2048 blocks x 512 thr (8 waves), block owns 32 batch rows.
// All 3 edges processed TOGETHER per K-step: each B-fragment feeds 3 edges x 2
// row-tiles = 24 MFMAs (3x the latency cover of R11; W1/W2 read once per block
// not 3x -> block B-traffic 2.56 MB -> 1 MB). Barriers per pass: 4 (was ~10).
// LDS map (144 KB, 1 block/CU):
//   h1s[e]  : e*32768,      [0, 96K)   — layer1 out / layer2 A-source
//   ebuf[e] : 96K + e*16384 [96K,144K) — staged edge inputs (layer1 A-source)
//   aggb    : 96K, 32 KB    — agg (bf16) reuses dead ebuf after layer1
//   zbuf    : [0, 32K) fp32 — reuses h1s[0] after layer2 (layer3 reads aggb only)
// REGISTERS: c 96 + A-pp 48 + B-pp 32 + bias 10 + addr ~15 ~= 200.
// amdgpu_waves_per_eu(2,2) pins 2 waves/EU -> 256-VGPR cap AND stops the
// allocator's occupancy-greed (R12: launch_bounds min alone let it pick 8
// waves/EU -> 64 regs -> 1 GB spills). Do not replace with __launch_bounds__ arg2.
__global__ __launch_bounds__(512) __attribute__((amdgpu_waves_per_eu(2, 2)))
void k_fused(const float* __restrict__ x,
             const unsigned short* __restrict__ w1p,
             const unsigned short* __restrict__ w2p,
             const unsigned short* __restrict__ w3p,
             const float* __restrict__ b1, const float* __restrict__ b2,
             const float* __restrict__ b3,
             float* __restrict__ out,
             float* __restrict__ psum, float* __restrict__ psumsq) {
    __shared__ __align__(16) unsigned char smem[147456];
    unsigned char* h1b  = smem;             // 3 x 32 KB
    unsigned char* ebb  = smem + 98304;     // 3 x 16 KB
    unsigned char* aggb = smem + 98304;     // 32 KB (aliases ebuf0+ebuf1)
    float* zbuf = (float*)smem;             // 32 KB (aliases h1s[0])

    const int tid = threadIdx.x;
    const int w   = tid >> 6;
    const int l   = tid & 63;
    const int l15 = l & 15;
    const int lg  = l >> 4;
    const int blk = blockIdx.x;
    const int row0 = blk * BM;

    const int sr  = tid & 31;
    const int skg = tid >> 5;
    const float* xrow = x + (size_t)(row0 + sr) * 768;

    float bias1[4], bias2[4];
#pragma unroll
    for (int nt = 0; nt < 4; ++nt) {
        bias1[nt] = b1[w * 64 + nt * 16 + l15];
        bias2[nt] = b2[w * 64 + nt * 16 + l15];
    }
    float bias3[2];
#pragma unroll
    for (int nt = 0; nt < 2; ++nt) bias3[nt] = b3[w * 32 + nt * 16 + l15];

    // ---- stage all 3 edge buffers (x loaded once per node) ----
#pragma unroll
    for (int h = 0; h < 2; ++h) {
        int kg = skg + h * 16;
        float4 n0a = *(const float4*)(xrow + kg * 8);
        float4 n0b = *(const float4*)(xrow + kg * 8 + 4);
        float4 n1a = *(const float4*)(xrow + 256 + kg * 8);
        float4 n1b = *(const float4*)(xrow + 256 + kg * 8 + 4);
        float4 n2a = *(const float4*)(xrow + 512 + kg * 8);
        float4 n2b = *(const float4*)(xrow + 512 + kg * 8 + 4);
        *(uint4*)(ebb + cellb(kg, sr))         = pack8(n0a, n0b, n1a, n1b);  // e01
        *(uint4*)(ebb + 16384 + cellb(kg, sr)) = pack8(n0a, n0b, n2a, n2b);  // e02
        *(uint4*)(ebb + 32768 + cellb(kg, sr)) = pack8(n1a, n1b, n2a, n2b);  // e12
    }

    // ---- layer1: c1[e] = e @ W1  (K=256, 8 kt, B shared across 3 edges) ----
    f32x4 c1[3][2][4];
#pragma unroll
    for (int e = 0; e < 3; ++e)
#pragma unroll
        for (int mt = 0; mt < 2; ++mt)
#pragma unroll
            for (int nt = 0; nt < 4; ++nt) c1[e][mt][nt] = (f32x4){0.f, 0.f, 0.f, 0.f};

    {
        short8 aP[3][2], aQ[3][2], bP[4], bQ[4];
#pragma unroll
        for (int nt = 0; nt < 4; ++nt)
            bP[nt] = *(const short8*)(w1p + (((w * 4 + nt) * 8) * 64 + l) * 8);
        __syncthreads();   // ebuf ready
#pragma unroll
        for (int e = 0; e < 3; ++e)
#pragma unroll
            for (int mt = 0; mt < 2; ++mt)
                aP[e][mt] = *(const short8*)(ebb + e * 16384 + cellb(lg, mt * 16 + l15));
#pragma unroll 1
        for (int kt = 0; kt < 8; kt += 2) {
#pragma unroll
            for (int e = 0; e < 3; ++e)
#pragma unroll
                for (int mt = 0; mt < 2; ++mt)
                    aQ[e][mt] = *(const short8*)(ebb + e * 16384 + cellb((kt + 1) * 4 + lg, mt * 16 + l15));
#pragma unroll
            for (int nt = 0; nt < 4; ++nt)
                bQ[nt] = *(const short8*)(w1p + (((w * 4 + nt) * 8 + kt + 1) * 64 + l) * 8);
            __builtin_amdgcn_s_setprio(1);
#pragma unroll
            for (int nt = 0; nt < 4; ++nt)
#pragma unroll
                for (int e = 0; e < 3; ++e)
#pragma unroll
                    for (int mt = 0; mt < 2; ++mt)
                        c1[e][mt][nt] = __builtin_amdgcn_mfma_f32_16x16x32_bf16(aP[e][mt], bP[nt], c1[e][mt][nt], 0, 0, 0);
            __builtin_amdgcn_s_setprio(0);
            if (kt + 2 < 8) {
#pragma unroll
                for (int e = 0; e < 3; ++e)
#pragma unroll
                    for (int mt = 0; mt < 2; ++mt)
                        aP[e][mt] = *(const short8*)(ebb + e * 16384 + cellb((kt + 2) * 4 + lg, mt * 16 + l15));
#pragma unroll
                for (int nt = 0; nt < 4; ++nt)
                    bP[nt] = *(const short8*)(w1p + (((w * 4 + nt) * 8 + kt + 2) * 64 + l) * 8);
            }
            __builtin_amdgcn_s_setprio(1);
#pragma unroll
            for (int nt = 0; nt < 4; ++nt)
#pragma unroll
                for (int e = 0; e < 3; ++e)
#pragma unroll
                    for (int mt = 0; mt < 2; ++mt)
                        c1[e][mt][nt] = __builtin_amdgcn_mfma_f32_16x16x32_bf16(aQ[e][mt], bQ[nt], c1[e][mt][nt], 0, 0, 0);
            __builtin_amdgcn_s_setprio(0);
        }
    }

    // ---- layer1 epilogue: relu(c1+b1) -> h1s[e] (bf16, k-packed) ----
#pragma unroll
    for (int e = 0; e < 3; ++e)
#pragma unroll
        for (int nt = 0; nt < 4; ++nt) {
            int c = w * 64 + nt * 16 + l15;
#pragma unroll
            for (int mt = 0; mt < 2; ++mt)
#pragma unroll
                for (int reg = 0; reg < 4; ++reg) {
                    int r = mt * 16 + lg * 4 + reg;
                    float v = c1[e][mt][nt][reg] + bias1[nt];
                    v = v > 0.f ? v : 0.f;
                    *(unsigned short*)(h1b + e * 32768 + cellb(c >> 3, r) + ((c & 7) << 1)) = f2bf(v);
                }
        }
    __syncthreads();   // h1s ready; ebuf reads done (aggb overwrite safe later)

    // ---- layer2: c2[e] = h1[e] @ W2  (K=512, 16 kt, B shared across edges) ----
    f32x4 c2[3][2][4];
#pragma unroll
    for (int e = 0; e < 3; ++e)
#pragma unroll
        for (int mt = 0; mt < 2; ++mt)
#pragma unroll
            for (int nt = 0; nt < 4; ++nt) c2[e][mt][nt] = (f32x4){0.f, 0.f, 0.f, 0.f};

    {
        short8 aP[3][2], aQ[3][2], bP[4], bQ[4];
#pragma unroll
        for (int nt = 0; nt < 4; ++nt)
            bP[nt] = *(const short8*)(w2p + (((w * 4 + nt) * 16) * 64 + l) * 8);
#pragma unroll
        for (int e = 0; e < 3; ++e)
#pragma unroll
            for (int mt = 0; mt < 2; ++mt)
                aP[e][mt] = *(const short8*)(h1b + e * 32768 + cellb(lg, mt * 16 + l15));
#pragma unroll 1
        for (int kt = 0; kt < 16; kt += 2) {
#pragma unroll
            for (int e = 0; e < 3; ++e)
#pragma unroll
                for (int mt = 0; mt < 2; ++mt)
                    aQ[e][mt] = *(const short8*)(h1b + e * 32768 + cellb((kt + 1) * 4 + lg, mt * 16 + l15));
#pragma unroll
            for (int nt = 0; nt < 4; ++nt)
                bQ[nt] = *(const short8*)(w2p + (((w * 4 + nt) * 16 + kt + 1) * 64 + l) * 8);
            __builtin_amdgcn_s_setprio(1);
#pragma unroll
            for (int nt = 0; nt < 4; ++nt)
#pragma unroll
                for (int e = 0; e < 3; ++e)
#pragma unroll
                    for (int mt = 0; mt < 2; ++mt)
                        c2[e][mt][nt] = __builtin_amdgcn_mfma_f32_16x16x32_bf16(aP[e][mt], bP[nt], c2[e][mt][nt], 0, 0, 0);
            __builtin_amdgcn_s_setprio(0);
            if (kt + 2 < 16) {
#pragma unroll
                for (int e = 0; e < 3; ++e)
#pragma unroll
                    for (int mt = 0; mt < 2; ++mt)
                        aP[e][mt] = *(const short8*)(h1b + e * 32768 + cellb((kt + 2) * 4 + lg, mt * 16 + l15));
#pragma unroll
                for (int nt = 0; nt < 4; ++nt)
                    bP[nt] = *(const short8*)(w2p + (((w * 4 + nt) * 16 + kt + 2) * 64 + l) * 8);
            }
            __builtin_amdgcn_s_setprio(1);
#pragma unroll
            for (int nt = 0; nt < 4; ++nt)
#pragma unroll
                for (int e = 0; e < 3; ++e)
#pragma unroll
                    for (int mt = 0; mt < 2; ++mt)
                        c2[e][mt][nt] = __builtin_amdgcn_mfma_f32_16x16x32_bf16(aQ[e][mt], bQ[nt], c2[e][mt][nt], 0, 0, 0);
            __builtin_amdgcn_s_setprio(0);
        }
    }

    // ---- agg = sum_e relu(c2[e]+b2) -> aggb (bf16; dead ebuf region) ----
#pragma unroll
    for (int nt = 0; nt < 4; ++nt) {
        int c = w * 64 + nt * 16 + l15;
#pragma unroll
        for (int mt = 0; mt < 2; ++mt)
#pragma unroll
            for (int reg = 0; reg < 4; ++reg) {
                int r = mt * 16 + lg * 4 + reg;
                float s = 0.f;
#pragma unroll
                for (int e = 0; e < 3; ++e) {
                    float v = c2[e][mt][nt][reg] + bias2[nt];
                    s += (v > 0.f ? v : 0.f);
                }
                *(unsigned short*)(aggb + cellb(c >> 3, r) + ((c & 7) << 1)) = f2bf(s);
            }
    }
    __syncthreads();   // aggb complete; h1s reads all done

    // ---- layer3: z = agg @ W3 + b3  (K=512, wave owns 32 cols, ping-pong) ----
    f32x4 c3[2][2];
#pragma unroll
    for (int mt = 0; mt < 2; ++mt)
#pragma unroll
        for (int nt = 0; nt < 2; ++nt) c3[mt][nt] = (f32x4){0.f, 0.f, 0.f, 0.f};

    {
        short8 aP[2], aQ[2], bP[2], bQ[2];
#pragma unroll
        for (int nt = 0; nt < 2; ++nt)
            bP[nt] = *(const short8*)(w3p + (((w * 2 + nt) * 16) * 64 + l) * 8);
#pragma unroll
        for (int mt = 0; mt < 2; ++mt)
            aP[mt] = *(const short8*)(aggb + cellb(lg, mt * 16 + l15));
#pragma unroll 1
        for (int kt = 0; kt < 16; kt += 2) {
#pragma unroll
            for (int mt = 0; mt < 2; ++mt)
                aQ[mt] = *(const short8*)(aggb + cellb((kt + 1) * 4 + lg, mt * 16 + l15));
#pragma unroll
            for (int nt = 0; nt < 2; ++nt)
                bQ[nt] = *(const short8*)(w3p + (((w * 2 + nt) * 16 + kt + 1) * 64 + l) * 8);
            __builtin_amdgcn_s_setprio(1);
#pragma unroll
            for (int nt = 0; nt < 2; ++nt)
#pragma unroll
                for (int mt = 0; mt < 2; ++mt)
                    c3[mt][nt] = __builtin_amdgcn_mfma_f32_16x16x32_bf16(aP[mt], bP[nt], c3[mt][nt], 0, 0, 0);
            __builtin_amdgcn_s_setprio(0);
            if (kt + 2 < 16) {
#pragma unroll
                for (int mt = 0; mt < 2; ++mt)
                    aP[mt] = *(const short8*)(aggb + cellb((kt + 2) * 4 + lg, mt * 16 + l15));
#pragma unroll
                for (int nt = 0; nt < 2; ++nt)
                    bP[nt] = *(const short8*)(w3p + (((w * 2 + nt) * 16 + kt + 2) * 64 + l) * 8);
            }
            __builtin_amdgcn_s_setprio(1);
#pragma unroll
            for (int nt = 0; nt < 2; ++nt)
#pragma unroll
                for (int mt = 0; mt < 2; ++mt)
                    c3[mt][nt] = __builtin_amdgcn_mfma_f32_16x16x32_bf16(aQ[mt], bQ[nt], c3[mt][nt], 0, 0, 0);
            __builtin_amdgcn_s_setprio(0);
        }
    }

    // ---- z epilogue: zbuf (h1s[0] region — disjoint from aggb) + BN partials ----
#pragma unroll
    for (int nt = 0; nt < 2; ++nt) {
        int c = w * 32 + nt * 16 + l15;
        float s = 0.f, q = 0.f;
#pragma unroll
        for (int mt = 0; mt < 2; ++mt)
#pragma unroll
            for (int reg = 0; reg < 4; ++reg) {
                int r = mt * 16 + lg * 4 + reg;
                float v = c3[mt][nt][reg] + bias3[nt];
                zbuf[r * 256 + c] = v;
                s += v;
                q += v * v;
            }
        s += __shfl_xor(s, 16); s += __shfl_xor(s, 32);
        q += __shfl_xor(q, 16); q += __shfl_xor(q, 32);
        if (lg == 0) {
            psum[c * NBLK + blk] = s;
            psumsq[c * NBLK + blk] = q;
        }
    }
    __syncthreads();
    {
        const float4* zb4 = (const float4*)zbuf;
        float4* o4 = (float4*)(out + (size_t)row0 * 256);
#pragma unroll
        for (int i = 0; i < 4; ++i)
            o4[tid + i * 512] = zb4[tid + i * 512];
    }
}

// ---------------- K2: reduce 2048 partials -> scale/shift ----------------
__global__ void k_stats2(const float* __restrict__ psum, const float* __restrict__ psumsq,
                         const float* __restrict__ gamma, const float* __restrict__ beta,
                         float* __restrict__ scale, float* __restrict__ shift) {
    int f = blockIdx.x, t = threadIdx.x;
    const float* ps = psum + f * NBLK;
    const float* pq = psumsq + f * NBLK;
    float s = 0.f, q = 0.f;
#pragma unroll
    for (int i = 0; i < 8; ++i) {
        s += ps[t + i * 256];
        q += pq[t + i * 256];
    }
#pragma unroll
    for (int o = 32; o > 0; o >>= 1) {
        s += __shfl_down(s, o);
        q += __shfl_down(q, o);
    }
    __shared__ float ls[4], lq[4];
    if ((t & 63) == 0) { ls[t >> 6] = s; lq[t >> 6] = q; }
    __syncthreads();
    if (t == 0) {
        s = ls[0] + ls[1] + ls[2] + ls[3];
        q = lq[0] + lq[1] + lq[2] + lq[3];
        float mu  = s * (1.f / 65536.f);
        float var = q * (1.f / 65536.f) - mu * mu;
        float sc  = gamma[f] * rsqrtf(var + EPS);
        scale[f] = sc;
        shift[f] = beta[f] - mu * sc;
    }
}

// ---------------- K3: in-place normalize of d_out ----------------
__global__ void k_norm(float4* __restrict__ out4, const float4* __restrict__ scale4,
                       const float4* __restrict__ shift4, int n4) {
    int i = blockIdx.x * blockDim.x + threadIdx.x;
    int stride = gridDim.x * blockDim.x;
    for (; i < n4; i += stride) {
        float4 v = out4[i];
        float4 sc = scale4[i & 63];
        float4 sh = shift4[i & 63];
        v.x = v.x * sc.x + sh.x;
        v.y = v.y * sc.y + sh.y;
        v.z = v.z * sc.z + sh.z;
        v.w = v.w * sc.w + sh.w;
        out4[i] = v;
    }
}

extern "C" void kernel_launch(void* const* d_in, const int* in_sizes, int n_in,
                              void* d_out, int out_size, void* d_ws, size_t ws_size,
                              hipStream_t stream) {
    const float* x     = (const float*)d_in[0];
    const float* W1    = (const float*)d_in[1];
    const float* b1    = (const float*)d_in[2];
    const float* W2    = (const float*)d_in[3];
    const float* b2    = (const float*)d_in[4];
    const float* W3    = (const float*)d_in[5];
    const float* b3    = (const float*)d_in[6];
    const float* gamma = (const float*)d_in[7];
    const float* beta  = (const float*)d_in[8];

    char* ws = (char*)d_ws;
    unsigned short* w1p = (unsigned short*)(ws);            // 256 KB
    unsigned short* w2p = (unsigned short*)(ws + 262144);   // 512 KB
    unsigned short* w3p = (unsigned short*)(ws + 786432);   // 256 KB
    float* psum   = (float*)(ws + 1048576);                 // 2 MB
    float* psumsq = (float*)(ws + 3145728);                 // 2 MB
    float* scale  = (float*)(ws + 5242880);                 // 1 KB
    float* shift  = (float*)(ws + 5243904);                 // 1 KB

    float* out = (float*)d_out;

    k_prep<<<2048, 256, 0, stream>>>(W1, W2, W3, w1p, w2p, w3p);
    k_fused<<<NBLK, 512, 0, stream>>>(x, w1p, w2p, w3p, b1, b2, b3, out, psum, psumsq);
    k_stats2<<<256, 256, 0, stream>>>(psum, psumsq, gamma, beta, scale, shift);
    k_norm<<<2048, 256, 0, stream>>>((float4*)out, (const float4*)scale, (const float4*)shift,
                                     (NROWS * 256) / 4);
}